// Round 4
// baseline (402.774 us; speedup 1.0000x reference)
//
#include <hip/hip_runtime.h>
#include <hip/hip_cooperative_groups.h>
#include <math.h>

namespace cg = cooperative_groups;

// Problem constants (match reference)
#define NB 2
#define NS 8
#define NA 24000
#define NC 80
#define NM 20
#define NCE 7
#define NBS (NB*NS)          // 16 frames
#define CPB 16               // chunks (blocks) per frame
#define APC (NA/CPB)         // anchors per chunk = 1500

#define POS_TH 0.5f
#define NEG_TH 0.4f
#define OMB 1e-4f            // 1.0 - 0.9999 (correctly rounded to f32)

// k_cls geometry: 480000 threads x 16 iters == NBS*NA*NC/4 float4s exactly
#define CLS_BLOCKS 1875
#define CLS_THREADS (CLS_BLOCKS * 256)   // 480000
#define CLS_ITERS 16

// pack (iou, anchor_idx) into u64 so max-reduce picks higher iou,
// tie -> smaller anchor index (argmax first-occurrence semantics)
__device__ inline unsigned long long packKey(float f, unsigned idx) {
    unsigned u = __float_as_uint(f);
    u = (u & 0x80000000u) ? ~u : (u | 0x80000000u);   // total order on floats
    return ((unsigned long long)u << 32) | (unsigned long long)(0xFFFFFFFFu - idx);
}

// =============== cooperative kernel: weights + IoU + match, fused ===============
// 256 blocks x 256 threads = 1 block/CU, fully co-resident -> grid.sync() legal.
// Block (bs,chunk) owns 1500 anchors; per-anchor best gt stays in LDS across phases.
__global__ void __launch_bounds__(256, 1)
k_main(const float* __restrict__ gtb, const int* __restrict__ counts,
       const float* __restrict__ anchors, const float* __restrict__ ploc,
       const float* __restrict__ gtl, const float* __restrict__ logits,
       const int* __restrict__ cls_num,
       unsigned long long* __restrict__ chunkbest,   // [256][NM], plain stores
       float* __restrict__ cmaskf,
       double* __restrict__ acc, int* __restrict__ npos, unsigned* __restrict__ ctr) {
    int bid = blockIdx.x;
    int bs = bid / CPB;
    int chunk = bid % CPB;
    int t = threadIdx.x;
    int cnt = counts[bs];
    int wave = t >> 6, lane = t & 63;

    __shared__ float sg[NM][5];        // x1,y1,x2,y2,area (gt already point form)
    __shared__ float sbt_iou[APC];     // per-anchor best iou (this chunk)
    __shared__ int   sbt_idx[APC];     // per-anchor best gt
    __shared__ unsigned long long sk[4][NM];
    __shared__ unsigned abest[NM];
    __shared__ float wsh[NC];
    __shared__ float wsum_sh;

    if (bid == 0 && t == 0) { acc[0] = 0.0; acc[1] = 0.0; *npos = 0; *ctr = 0u; }

    if (t < NM) {
        const float* g = gtb + ((size_t)bs * NM + t) * 4;
        float x1 = g[0], y1 = g[1], x2 = g[2], y2 = g[3];
        sg[t][0] = x1; sg[t][1] = y1; sg[t][2] = x2; sg[t][3] = y2;
        sg[t][4] = (x2 - x1) * (y2 - y1);
    }
    // CB weights, computed redundantly per block (80 powf — trivial)
    if (t < NC) {
        float n = (float)cls_num[t];
        wsh[t] = OMB / (1.0f - powf(0.9999f, n));
    }
    __syncthreads();
    if (t == 0) {
        float s = 0.0f;
        for (int c = 0; c < NC; c++) s += wsh[c];
        wsum_sh = s;
    }
    __syncthreads();
    if (t < NC) wsh[t] = wsh[t] / wsum_sh;

    // ---------------- phase 1: IoU ----------------
    unsigned long long bp[NM];
    #pragma unroll
    for (int m = 0; m < NM; m++) bp[m] = 0ULL;

    int a0 = chunk * APC;
    for (int a = a0 + t; a < a0 + APC; a += 256) {
        float4 cf = ((const float4*)anchors)[a];
        float ax1 = cf.x - cf.z * 0.5f, ay1 = cf.y - cf.w * 0.5f;
        float ax2 = cf.x + cf.z * 0.5f, ay2 = cf.y + cf.w * 0.5f;
        float aarea = (ax2 - ax1) * (ay2 - ay1);
        float best = -1.0f; int bm = 0;
        #pragma unroll
        for (int m = 0; m < NM; m++) {
            if (m < cnt) {
                float ltx = fmaxf(sg[m][0], ax1), lty = fmaxf(sg[m][1], ay1);
                float rbx = fminf(sg[m][2], ax2), rby = fminf(sg[m][3], ay2);
                float wx = fmaxf(rbx - ltx, 0.0f), wy = fmaxf(rby - lty, 0.0f);
                float inter = wx * wy;
                float iou = inter / (sg[m][4] + aarea - inter + 1e-10f);  // IEEE div: threshold-exact vs ref
                if (iou > best) { best = iou; bm = m; }   // strict >: first m wins ties
                unsigned long long k = packKey(iou, (unsigned)a);
                if (k > bp[m]) bp[m] = k;
            }
        }
        sbt_iou[a - a0] = best;
        sbt_idx[a - a0] = bm;
    }

    // per-wave shfl max, cross-wave via LDS, plain store to this block's slots
    for (int m = 0; m < cnt; m++) {       // cnt is block-uniform
        unsigned long long k = bp[m];
        #pragma unroll
        for (int off = 32; off > 0; off >>= 1) {
            unsigned long long o = __shfl_xor(k, off);
            if (o > k) k = o;
        }
        if (lane == 0) sk[wave][m] = k;
    }
    __syncthreads();
    if (t < NM) {
        unsigned long long k = 0ULL;
        if (t < cnt) {
            k = sk[0][t];
            if (sk[1][t] > k) k = sk[1][t];
            if (sk[2][t] > k) k = sk[2][t];
            if (sk[3][t] > k) k = sk[3][t];
        }
        chunkbest[bid * NM + t] = k;      // write all NM slots (poisoned ws!)
    }

    cg::this_grid().sync();

    // ---------------- phase 2: match + losses ----------------
    if (t < NM && t < cnt) {
        unsigned long long k = 0ULL;
        for (int c = 0; c < CPB; c++) {
            unsigned long long o = chunkbest[(bs * CPB + c) * NM + t];
            if (o > k) k = o;
        }
        abest[t] = 0xFFFFFFFFu - (unsigned)(k & 0xFFFFFFFFull);
    }
    __syncthreads();

    const float SL1B = 1.0f / 9.0f;
    float regsum = 0.0f, corrsum = 0.0f;
    int pcnt = 0;
    for (int a = a0 + t; a < a0 + APC; a += 256) {
        size_t ia = (size_t)bs * NA + a;
        float iou = sbt_iou[a - a0];
        int idx = sbt_idx[a - a0];
        for (int m = 0; m < cnt; m++) {           // ascending: last match wins
            if (abest[m] == (unsigned)a) { iou = 2.0f; idx = m; }
        }
        int code;
        if (cnt == 0) code = -1;
        else if (iou < NEG_TH) code = 0;
        else if (iou < POS_TH) code = -1;
        else code = idx + 1;
        cmaskf[ia] = (code == -1) ? 0.0f : 1.0f;
        if (code > 0) {
            pcnt++;
            float4 cf = ((const float4*)anchors)[a];
            float mx1 = sg[idx][0], my1 = sg[idx][1], mx2 = sg[idx][2], my2 = sg[idx][3];
            float g0 = ((mx1 + mx2) * 0.5f - cf.x) / (0.1f * cf.z);
            float g1 = ((my1 + my2) * 0.5f - cf.y) / (0.1f * cf.w);
            float g2 = logf(fmaxf(mx2 - mx1, 1e-6f) / cf.z) / 0.2f;
            float g3 = logf(fmaxf(my2 - my1, 1e-6f) / cf.w) / 0.2f;
            float4 p = ((const float4*)ploc)[ia];
            float n0 = fabsf(p.x - g0), n1 = fabsf(p.y - g1);
            float n2 = fabsf(p.z - g2), n3 = fabsf(p.w - g3);
            float s0 = n0 < SL1B ? 0.5f * n0 * n0 / SL1B : n0 - 0.5f * SL1B;
            float s1 = n1 < SL1B ? 0.5f * n1 * n1 / SL1B : n1 - 0.5f * SL1B;
            float s2 = n2 < SL1B ? 0.5f * n2 * n2 / SL1B : n2 - 0.5f * SL1B;
            float s3 = n3 < SL1B ? 0.5f * n3 * n3 / SL1B : n3 - 0.5f * SL1B;
            regsum += s0 + s1 + s2 + s3;

            // pos-class correction: corr = w*ls*(e*p) - OMB*(x+ls)*p
            const float4* yrow = (const float4*)(gtl + ((size_t)(bs * NM + idx)) * NC);
            const float4* xrow = (const float4*)(logits + ia * NC);
            #pragma unroll 4
            for (int c4 = 0; c4 < NC / 4; c4++) {
                float4 y4 = yrow[c4];
                if (y4.x > 0.5f || y4.y > 0.5f || y4.z > 0.5f || y4.w > 0.5f) {
                    float4 x4 = xrow[c4];
                    float yv[4] = {y4.x, y4.y, y4.z, y4.w};
                    float xv[4] = {x4.x, x4.y, x4.z, x4.w};
                    #pragma unroll
                    for (int j = 0; j < 4; j++) {
                        if (yv[j] > 0.5f) {
                            float x = xv[j];
                            float e = __expf(-x);
                            float s = 1.0f + e;
                            float pr = __builtin_amdgcn_rcpf(s);
                            float ls = __logf(s);
                            corrsum += ls * wsh[c4 * 4 + j] * (e * pr)
                                     - OMB * (x + ls) * pr;
                        }
                    }
                }
            }
        }
    }

    #pragma unroll
    for (int off = 32; off > 0; off >>= 1) {
        regsum  += __shfl_xor(regsum, off);
        corrsum += __shfl_xor(corrsum, off);
        pcnt    += __shfl_xor(pcnt, off);
    }
    __shared__ float sf[4], sc[4];
    __shared__ int   si[4];
    if (lane == 0) { sf[wave] = regsum; sc[wave] = corrsum; si[wave] = pcnt; }
    __syncthreads();
    if (t == 0) {
        atomicAdd(&acc[0], (double)(sf[0] + sf[1] + sf[2] + sf[3]));
        atomicAdd(&acc[1], (double)(sc[0] + sc[1] + sc[2] + sc[3]));
        atomicAdd(npos, si[0] + si[1] + si[2] + si[3]);
    }
}

// =============== k_cls: streaming background focal term + last-block final ===============
__global__ void __launch_bounds__(256)
k_cls(const float* __restrict__ logits, const float* __restrict__ cmaskf,
      const float* __restrict__ ego_preds, const int* __restrict__ ego_labels,
      double* __restrict__ acc, int* __restrict__ npos, unsigned* __restrict__ ctr,
      float* __restrict__ out) {
    unsigned tid = blockIdx.x * 256u + threadIdx.x;
    const float4* x4p = (const float4*)logits;

    float negsum = 0.0f;
    #pragma unroll
    for (int j = 0; j < CLS_ITERS; j++) {
        unsigned i = tid + (unsigned)j * (unsigned)CLS_THREADS;
        unsigned af = i / 20u;                 // const-divisor -> magic mul
        float msk = cmaskf[af];
        float4 x4 = x4p[i];
        float xv[4] = {x4.x, x4.y, x4.z, x4.w};
        float tsum = 0.0f;
        #pragma unroll
        for (int jj = 0; jj < 4; jj++) {
            float x = xv[jj];
            float e = __expf(-x);
            float s = 1.0f + e;
            float pr = __builtin_amdgcn_rcpf(s);
            float ls = __logf(s);
            tsum += (x + ls) * pr;
        }
        negsum = fmaf(msk, tsum, negsum);
    }
    float lsum = OMB * negsum;

    #pragma unroll
    for (int off = 32; off > 0; off >>= 1) lsum += __shfl_xor(lsum, off);
    __shared__ float sf[4];
    int t = threadIdx.x, wave = t >> 6, lane = t & 63;
    if (lane == 0) sf[wave] = lsum;
    __syncthreads();

    __shared__ unsigned lastflag;
    if (t == 0) {
        atomicAdd(&acc[1], (double)(sf[0] + sf[1] + sf[2] + sf[3]));
        __threadfence();
        unsigned d = atomicAdd(ctr, 1u);
        lastflag = (d == (unsigned)(CLS_BLOCKS - 1)) ? 1u : 0u;
    }
    __syncthreads();
    if (!lastflag) return;

    // ------- last block: ego focal loss + combine (all 256 threads reach barriers) -------
    __threadfence();
    __shared__ float scol[NCE];
    __shared__ float sred[128];
    __shared__ int   sval[128];
    const float EPSF = 1e-7f;
    if (t < NCE) {
        float c = 0.0f;
        for (int i = 0; i < NBS; i++) {
            int l = ego_labels[i];
            if (l > -1 && l == t) c = 1.0f;
        }
        scol[t] = c;
    }
    __syncthreads();

    float term = 0.0f;
    if (t < NBS * NCE) {
        int bs = t / NCE, e = t % NCE;
        int lbl = ego_labels[bs];
        if (lbl > -1) {
            float x = ego_preds[t];
            float ep = 1.0f / (1.0f + expf(-x));
            float oh = scol[e];
            float af = 0.25f * oh + 0.75f * (1.0f - oh);
            float ept = ep * oh + (1.0f - ep) * (1.0f - oh);
            float epc = fminf(fmaxf(ep, EPSF), 1.0f - EPSF);
            float bce = -(oh * logf(epc) + (1.0f - oh) * log1pf(-epc));
            float om = 1.0f - ept;
            term = bce * af * om * om;
        }
    }
    if (t < 128) { sred[t] = term; sval[t] = (t < NBS && ego_labels[t] > -1) ? 1 : 0; }
    __syncthreads();
    for (int off = 64; off > 0; off >>= 1) {
        if (t < off) { sred[t] += sred[t + off]; sval[t] += sval[t + off]; }
        __syncthreads();
    }
    if (t == 0) {
        float esum = sred[0];
        int ne = sval[0];
        float ego = (ne > 0) ? esum / (float)(ne > 1 ? ne : 1) : 0.0f;
        // L2-coherent reads of other blocks' atomic accumulations
        double rsum = atomicAdd(&acc[0], 0.0);
        double csum = atomicAdd(&acc[1], 0.0);
        int np = atomicAdd(npos, 0);
        double npd = (double)np;
        if (npd < 1.0) npd = 1.0;
        out[0] = (float)(rsum / (npd * 4.0));
        out[1] = (float)(csum / npd / 8.0 + (double)ego / 4.0);
    }
}

// ---------------- host launch ----------------
extern "C" void kernel_launch(void* const* d_in, const int* in_sizes, int n_in,
                              void* d_out, int out_size, void* d_ws, size_t ws_size,
                              hipStream_t stream) {
    const float* confidence = (const float*)d_in[0];
    const float* ploc       = (const float*)d_in[1];
    const float* gtb        = (const float*)d_in[2];
    const float* gtl        = (const float*)d_in[3];
    const int*   counts     = (const int*)d_in[4];
    const float* anchors    = (const float*)d_in[5];
    const float* ego_preds  = (const float*)d_in[6];
    const int*   ego_labels = (const int*)d_in[7];
    const int*   cls_num    = (const int*)d_in[8];
    float* out = (float*)d_out;

    // workspace layout
    char* ws = (char*)d_ws;
    double*   acc  = (double*)ws;                         // [0]=reg_sum, [1]=cls_sum
    int*      npos = (int*)(ws + 16);
    unsigned* ctr  = (unsigned*)(ws + 20);
    unsigned long long* chunkbest = (unsigned long long*)(ws + 64);   // 256*20 u64 = 40960
    float*    cmaskf = (float*)(ws + 64 + 40960);                     // 16*24000 f32

    {
        void* args[] = { (void*)&gtb, (void*)&counts, (void*)&anchors, (void*)&ploc,
                         (void*)&gtl, (void*)&confidence, (void*)&cls_num,
                         (void*)&chunkbest, (void*)&cmaskf,
                         (void*)&acc, (void*)&npos, (void*)&ctr };
        hipLaunchCooperativeKernel((void*)k_main, dim3(NBS * CPB), dim3(256),
                                   args, 0, stream);
    }
    k_cls<<<CLS_BLOCKS, 256, 0, stream>>>(confidence, cmaskf, ego_preds, ego_labels,
                                          acc, npos, ctr, out);
}

// Round 5
// 320.852 us; speedup vs baseline: 1.2553x; 1.2553x over previous
//
#include <hip/hip_runtime.h>
#include <math.h>

// Problem constants (match reference)
#define NB 2
#define NS 8
#define NA 24000
#define NC 80
#define NM 20
#define NCE 7
#define NBS (NB*NS)          // 16 frames
#define CPB 16               // chunks (blocks) per frame
#define APC (NA/CPB)         // anchors per chunk = 1500

#define POS_TH 0.5f
#define NEG_TH 0.4f
#define OMB 1e-4f            // 1.0 - 0.9999 (correctly rounded to f32)

// k_cls geometry: 480000 threads x 16 iters == NBS*NA*NC/4 float4s exactly
#define CLS_BLOCKS 1875
#define CLS_THREADS (CLS_BLOCKS * 256)   // 480000
#define CLS_ITERS 16

// pack (iou, anchor_idx) into u64 so that max-reduce picks higher iou,
// tie -> smaller anchor index (argmax first-occurrence semantics)
__device__ inline unsigned long long packKey(float f, unsigned idx) {
    unsigned u = __float_as_uint(f);
    u = (u & 0x80000000u) ? ~u : (u | 0x80000000u);   // total order on floats
    return ((unsigned long long)u << 32) | (unsigned long long)(0xFFFFFFFFu - idx);
}

// ---------------- kernel 1: CB weights w[80] + zero-init workspace ----------------
__global__ void k_weights(const int* __restrict__ cls_num, float* __restrict__ wbuf,
                          unsigned long long* __restrict__ bestp,
                          double* __restrict__ acc, int* __restrict__ npos) {
    __shared__ float s[128];
    int t = threadIdx.x;
    for (int i = t; i < NBS * NM; i += 128) bestp[i] = 0ULL;
    if (t == 0) { acc[0] = 0.0; acc[1] = 0.0; *npos = 0; }
    float raw = 0.0f;
    if (t < NC) {
        float n = (float)cls_num[t];
        raw = OMB / (1.0f - powf(0.9999f, n));   // numerator cancels in normalization
    }
    s[t] = raw;
    __syncthreads();
    for (int off = 64; off > 0; off >>= 1) {
        if (t < off) s[t] += s[t + off];
        __syncthreads();
    }
    float sum = s[0];
    if (t < NC) wbuf[t] = raw / sum;
}

// ---------------- kernel 2: IoU, per-anchor best gt, per-gt best anchor ----------------
__global__ void k_iou(const float* __restrict__ gtb, const int* __restrict__ counts,
                      const float* __restrict__ anchors,
                      float* __restrict__ bt_iou, int* __restrict__ bt_idx,
                      unsigned long long* __restrict__ bestp) {
    int bs = blockIdx.x / CPB;
    int chunk = blockIdx.x % CPB;
    int t = threadIdx.x;
    int cnt = counts[bs];

    __shared__ float sg[NM][5];   // x1,y1,x2,y2,area (gt already point form)
    if (t < NM) {
        const float* g = gtb + ((size_t)bs * NM + t) * 4;
        float x1 = g[0], y1 = g[1], x2 = g[2], y2 = g[3];
        sg[t][0] = x1; sg[t][1] = y1; sg[t][2] = x2; sg[t][3] = y2;
        sg[t][4] = (x2 - x1) * (y2 - y1);
    }
    __syncthreads();

    unsigned long long bp[NM];
    #pragma unroll
    for (int m = 0; m < NM; m++) bp[m] = 0ULL;

    int a0 = chunk * APC;
    for (int a = a0 + t; a < a0 + APC; a += blockDim.x) {
        float4 cf = ((const float4*)anchors)[a];
        float ax1 = cf.x - cf.z * 0.5f, ay1 = cf.y - cf.w * 0.5f;
        float ax2 = cf.x + cf.z * 0.5f, ay2 = cf.y + cf.w * 0.5f;
        float aarea = (ax2 - ax1) * (ay2 - ay1);
        float best = -1.0f; int bm = 0;
        #pragma unroll
        for (int m = 0; m < NM; m++) {
            if (m < cnt) {
                float ltx = fmaxf(sg[m][0], ax1), lty = fmaxf(sg[m][1], ay1);
                float rbx = fminf(sg[m][2], ax2), rby = fminf(sg[m][3], ay2);
                float wx = fmaxf(rbx - ltx, 0.0f), wy = fmaxf(rby - lty, 0.0f);
                float inter = wx * wy;
                float iou = inter / (sg[m][4] + aarea - inter + 1e-10f);  // IEEE div: threshold-exact vs ref
                if (iou > best) { best = iou; bm = m; }   // strict >: first m wins ties
                unsigned long long k = packKey(iou, (unsigned)a);
                if (k > bp[m]) bp[m] = k;
            }
        }
        bt_iou[(size_t)bs * NA + a] = best;
        bt_idx[(size_t)bs * NA + a] = bm;
    }

    // per-wave shfl max, then cross-wave via LDS, then one atomic per m
    __shared__ unsigned long long sk[4][NM];
    int wave = t >> 6, lane = t & 63;
    for (int m = 0; m < cnt; m++) {       // cnt is block-uniform
        unsigned long long k = bp[m];
        #pragma unroll
        for (int off = 32; off > 0; off >>= 1) {
            unsigned long long o = __shfl_xor(k, off);
            if (o > k) k = o;
        }
        if (lane == 0) sk[wave][m] = k;
    }
    __syncthreads();
    if (t < cnt) {
        unsigned long long k = sk[0][t];
        if (sk[1][t] > k) k = sk[1][t];
        if (sk[2][t] > k) k = sk[2][t];
        if (sk[3][t] > k) k = sk[3][t];
        atomicMax(&bestp[bs * NM + t], k);
    }
}

// ---------------- kernel 3: conf mask, regression loss, and pos-class correction ------
// Force-match resolved inline: compare anchor id against the <=20 per-gt best anchors
// (ascending m scan == last-write-wins, numpy scatter semantics).
// For pos anchors, also computes the cls-loss correction for y==1 elements:
//   corr = w*ls*(e*p) - OMB*(x+ls)*p   (k_cls adds the OMB neg term for everything)
__global__ void k_match(const float* __restrict__ gtb, const int* __restrict__ counts,
                        const float* __restrict__ anchors, const float* __restrict__ ploc,
                        const float* __restrict__ gtl, const float* __restrict__ logits,
                        const float* __restrict__ wbuf,
                        const unsigned long long* __restrict__ bestp,
                        const float* __restrict__ bt_iou, const int* __restrict__ bt_idx,
                        float* __restrict__ cmaskf,
                        double* __restrict__ acc, int* __restrict__ npos) {
    int bs = blockIdx.x / CPB;
    int chunk = blockIdx.x % CPB;
    int t = threadIdx.x;
    int cnt = counts[bs];

    __shared__ float sg[NM][4];
    __shared__ unsigned abest[NM];
    __shared__ float wsh[NC];
    if (t < NM) {
        const float* g = gtb + ((size_t)bs * NM + t) * 4;
        sg[t][0] = g[0]; sg[t][1] = g[1]; sg[t][2] = g[2]; sg[t][3] = g[3];
    }
    if (t < cnt) {
        unsigned long long k = bestp[bs * NM + t];
        abest[t] = 0xFFFFFFFFu - (unsigned)(k & 0xFFFFFFFFull);
    }
    if (t < NC) wsh[t] = wbuf[t];
    __syncthreads();

    const float SL1B = 1.0f / 9.0f;
    float regsum = 0.0f, corrsum = 0.0f;
    int pcnt = 0;
    int a0 = chunk * APC;
    for (int a = a0 + t; a < a0 + APC; a += blockDim.x) {
        size_t ia = (size_t)bs * NA + a;
        float iou = bt_iou[ia];
        int idx = bt_idx[ia];
        for (int m = 0; m < cnt; m++) {           // ascending: last match wins
            if (abest[m] == (unsigned)a) { iou = 2.0f; idx = m; }
        }
        int code;
        if (cnt == 0) code = -1;
        else if (iou < NEG_TH) code = 0;
        else if (iou < POS_TH) code = -1;
        else code = idx + 1;
        cmaskf[ia] = (code == -1) ? 0.0f : 1.0f;
        if (code > 0) {
            pcnt++;
            float4 cf = ((const float4*)anchors)[a];
            float mx1 = sg[idx][0], my1 = sg[idx][1], mx2 = sg[idx][2], my2 = sg[idx][3];
            float g0 = ((mx1 + mx2) * 0.5f - cf.x) / (0.1f * cf.z);
            float g1 = ((my1 + my2) * 0.5f - cf.y) / (0.1f * cf.w);
            float g2 = logf(fmaxf(mx2 - mx1, 1e-6f) / cf.z) / 0.2f;
            float g3 = logf(fmaxf(my2 - my1, 1e-6f) / cf.w) / 0.2f;
            float4 p = ((const float4*)ploc)[ia];
            float n0 = fabsf(p.x - g0), n1 = fabsf(p.y - g1);
            float n2 = fabsf(p.z - g2), n3 = fabsf(p.w - g3);
            float s0 = n0 < SL1B ? 0.5f * n0 * n0 / SL1B : n0 - 0.5f * SL1B;
            float s1 = n1 < SL1B ? 0.5f * n1 * n1 / SL1B : n1 - 0.5f * SL1B;
            float s2 = n2 < SL1B ? 0.5f * n2 * n2 / SL1B : n2 - 0.5f * SL1B;
            float s3 = n3 < SL1B ? 0.5f * n3 * n3 / SL1B : n3 - 0.5f * SL1B;
            regsum += s0 + s1 + s2 + s3;

            // ---- pos-class correction over this anchor's 80 classes ----
            const float4* yrow = (const float4*)(gtl + ((size_t)(bs * NM + idx)) * NC);
            const float4* xrow = (const float4*)(logits + ia * NC);
            #pragma unroll 4
            for (int c4 = 0; c4 < NC / 4; c4++) {
                float4 y4 = yrow[c4];
                if (y4.x > 0.5f || y4.y > 0.5f || y4.z > 0.5f || y4.w > 0.5f) {
                    float4 x4 = xrow[c4];
                    float yv[4] = {y4.x, y4.y, y4.z, y4.w};
                    float xv[4] = {x4.x, x4.y, x4.z, x4.w};
                    #pragma unroll
                    for (int j = 0; j < 4; j++) {
                        if (yv[j] > 0.5f) {
                            float x = xv[j];
                            float e = __expf(-x);
                            float s = 1.0f + e;
                            float pr = __builtin_amdgcn_rcpf(s);
                            float ls = __logf(s);
                            corrsum += ls * wsh[c4 * 4 + j] * (e * pr)
                                     - OMB * (x + ls) * pr;
                        }
                    }
                }
            }
        }
    }

    // wave shfl-reduce then cross-wave LDS then one atomic per block
    #pragma unroll
    for (int off = 32; off > 0; off >>= 1) {
        regsum  += __shfl_xor(regsum, off);
        corrsum += __shfl_xor(corrsum, off);
        pcnt    += __shfl_xor(pcnt, off);
    }
    __shared__ float sf[4], sc[4];
    __shared__ int   si[4];
    int wave = t >> 6, lane = t & 63;
    if (lane == 0) { sf[wave] = regsum; sc[wave] = corrsum; si[wave] = pcnt; }
    __syncthreads();
    if (t == 0) {
        atomicAdd(&acc[0], (double)(sf[0] + sf[1] + sf[2] + sf[3]));
        atomicAdd(&acc[1], (double)(sc[0] + sc[1] + sc[2] + sc[3]));
        atomicAdd(npos, si[0] + si[1] + si[2] + si[3]);
    }
}

// ---------------- kernel 4: streaming background focal term (batch-8 MLP) ----------------
// Every non-ignore element contributes OMB*(x+log s)*p; pos y==1 elements were
// pre-corrected in k_match. Loads staged in batches of 8 float4 + 8 masks so the
// compiler keeps ~8-16 loads in flight (needs ~56-64 VGPR, still 8 waves/SIMD).
__global__ void __launch_bounds__(256)
k_cls(const float* __restrict__ logits, const float* __restrict__ cmaskf,
      double* __restrict__ acc) {
    unsigned tid = blockIdx.x * 256u + threadIdx.x;
    const float4* x4p = (const float4*)logits;

    float negsum = 0.0f;
    #pragma unroll
    for (int half = 0; half < 2; half++) {
        float4 xs[8];
        float  ms[8];
        #pragma unroll
        for (int j = 0; j < 8; j++) {
            unsigned i = tid + (unsigned)(half * 8 + j) * (unsigned)CLS_THREADS;
            ms[j] = cmaskf[i / 20u];        // const-divisor -> magic mul
            xs[j] = x4p[i];
        }
        #pragma unroll
        for (int j = 0; j < 8; j++) {
            float xv[4] = {xs[j].x, xs[j].y, xs[j].z, xs[j].w};
            float tsum = 0.0f;
            #pragma unroll
            for (int jj = 0; jj < 4; jj++) {
                float x = xv[jj];
                float e = __expf(-x);
                float s = 1.0f + e;
                float pr = __builtin_amdgcn_rcpf(s);
                float ls = __logf(s);
                tsum += (x + ls) * pr;
            }
            negsum = fmaf(ms[j], tsum, negsum);
        }
    }
    float lsum = OMB * negsum;

    #pragma unroll
    for (int off = 32; off > 0; off >>= 1) lsum += __shfl_xor(lsum, off);
    __shared__ float sf[4];
    int t = threadIdx.x, wave = t >> 6, lane = t & 63;
    if (lane == 0) sf[wave] = lsum;
    __syncthreads();
    if (t == 0) atomicAdd(&acc[1], (double)(sf[0] + sf[1] + sf[2] + sf[3]));
}

// ---------------- kernel 5: ego focal loss + final combine ----------------
__global__ void k_final(const float* __restrict__ ego_preds, const int* __restrict__ ego_labels,
                        const double* __restrict__ acc, const int* __restrict__ npos,
                        float* __restrict__ out) {
    __shared__ float scol[NCE];
    __shared__ float sred[128];
    __shared__ int   sval[128];
    const float EPSF = 1e-7f;
    int t = threadIdx.x;
    if (t < NCE) {
        float c = 0.0f;
        for (int i = 0; i < NBS; i++) {
            int l = ego_labels[i];
            if (l > -1 && l == t) c = 1.0f;
        }
        scol[t] = c;
    }
    __syncthreads();

    float term = 0.0f;
    if (t < NBS * NCE) {
        int bs = t / NCE, e = t % NCE;
        int lbl = ego_labels[bs];
        if (lbl > -1) {
            float x = ego_preds[t];
            float ep = 1.0f / (1.0f + expf(-x));
            float oh = scol[e];
            float af = 0.25f * oh + 0.75f * (1.0f - oh);
            float ept = ep * oh + (1.0f - ep) * (1.0f - oh);
            float epc = fminf(fmaxf(ep, EPSF), 1.0f - EPSF);
            float bce = -(oh * logf(epc) + (1.0f - oh) * log1pf(-epc));
            float om = 1.0f - ept;
            term = bce * af * om * om;
        }
    }
    sred[t] = term;
    sval[t] = (t < NBS && ego_labels[t] > -1) ? 1 : 0;
    __syncthreads();
    for (int off = 64; off > 0; off >>= 1) {
        if (t < off) { sred[t] += sred[t + off]; sval[t] += sval[t + off]; }
        __syncthreads();
    }
    if (t == 0) {
        float esum = sred[0];
        int ne = sval[0];
        float ego = (ne > 0) ? esum / (float)(ne > 1 ? ne : 1) : 0.0f;
        double npd = (double)(*npos);
        if (npd < 1.0) npd = 1.0;
        out[0] = (float)(acc[0] / (npd * 4.0));
        out[1] = (float)(acc[1] / npd / 8.0 + (double)ego / 4.0);
    }
}

// ---------------- host launch ----------------
extern "C" void kernel_launch(void* const* d_in, const int* in_sizes, int n_in,
                              void* d_out, int out_size, void* d_ws, size_t ws_size,
                              hipStream_t stream) {
    const float* confidence = (const float*)d_in[0];
    const float* ploc       = (const float*)d_in[1];
    const float* gtb        = (const float*)d_in[2];
    const float* gtl        = (const float*)d_in[3];
    const int*   counts     = (const int*)d_in[4];
    const float* anchors    = (const float*)d_in[5];
    const float* ego_preds  = (const float*)d_in[6];
    const int*   ego_labels = (const int*)d_in[7];
    const int*   cls_num    = (const int*)d_in[8];
    float* out = (float*)d_out;

    // workspace layout (16B aligned chunks)
    char* ws = (char*)d_ws;
    double* acc  = (double*)ws;                               // [0]=reg_sum, [1]=cls_sum
    int* npos    = (int*)(ws + 16);
    float* wbuf  = (float*)(ws + 32);                         // 80 floats
    unsigned long long* bestp = (unsigned long long*)(ws + 352);  // 16*20 u64
    float* bt_iou = (float*)(ws + 2944);                      // 16*24000 f32
    int*   bt_idx = (int*)(ws + 2944 + 1536000);              // 16*24000 i32
    float* cmaskf = (float*)(ws + 2944 + 3072000);            // 16*24000 f32

    k_weights<<<1, 128, 0, stream>>>(cls_num, wbuf, bestp, acc, npos);
    k_iou<<<NBS * CPB, 256, 0, stream>>>(gtb, counts, anchors, bt_iou, bt_idx, bestp);
    k_match<<<NBS * CPB, 256, 0, stream>>>(gtb, counts, anchors, ploc, gtl, confidence,
                                           wbuf, bestp, bt_iou, bt_idx, cmaskf, acc, npos);
    k_cls<<<CLS_BLOCKS, 256, 0, stream>>>(confidence, cmaskf, acc);
    k_final<<<1, 128, 0, stream>>>(ego_preds, ego_labels, acc, npos, out);
}

// Round 6
// 284.121 us; speedup vs baseline: 1.4176x; 1.1293x over previous
//
#include <hip/hip_runtime.h>
#include <math.h>

// Problem constants (match reference)
#define NB 2
#define NS 8
#define NA 24000
#define NC 80
#define NM 20
#define NCE 7
#define NBS (NB*NS)          // 16 frames
#define CPB 64               // chunks (blocks) per frame
#define APC (NA/CPB)         // anchors per chunk = 375

#define POS_TH 0.5f
#define NEG_TH 0.4f
#define OMB 1e-4f            // 1.0 - 0.9999 (correctly rounded to f32)

// pack (iou, anchor_idx) into u64 so that max-reduce picks higher iou,
// tie -> smaller anchor index (argmax first-occurrence semantics)
__device__ inline unsigned long long packKey(float f, unsigned idx) {
    unsigned u = __float_as_uint(f);
    u = (u & 0x80000000u) ? ~u : (u | 0x80000000u);   // total order on floats
    return ((unsigned long long)u << 32) | (unsigned long long)(0xFFFFFFFFu - idx);
}

// ---------------- kernel 1: IoU, per-anchor best gt, per-(gt,chunk) best anchor -------
// Also zero-inits the accumulators (block 0) — safe: they're consumed only by later
// kernels on the same stream (kernel-boundary coherence).
__global__ void __launch_bounds__(256)
k_iou(const float* __restrict__ gtb, const int* __restrict__ counts,
      const float* __restrict__ anchors,
      float* __restrict__ bt_iou, int* __restrict__ bt_idx,
      unsigned long long* __restrict__ chunkbest,
      double* __restrict__ acc, int* __restrict__ npos) {
    int bid = blockIdx.x;
    int bs = bid / CPB;
    int chunk = bid % CPB;
    int t = threadIdx.x;
    int cnt = counts[bs];

    if (bid == 0 && t == 0) { acc[0] = 0.0; acc[1] = 0.0; *npos = 0; }

    __shared__ float sg[NM][5];   // x1,y1,x2,y2,area (gt already point form)
    if (t < NM) {
        const float* g = gtb + ((size_t)bs * NM + t) * 4;
        float x1 = g[0], y1 = g[1], x2 = g[2], y2 = g[3];
        sg[t][0] = x1; sg[t][1] = y1; sg[t][2] = x2; sg[t][3] = y2;
        sg[t][4] = (x2 - x1) * (y2 - y1);
    }
    __syncthreads();

    unsigned long long bp[NM];
    #pragma unroll
    for (int m = 0; m < NM; m++) bp[m] = 0ULL;

    int a0 = chunk * APC;
    for (int a = a0 + t; a < a0 + APC; a += 256) {
        float4 cf = ((const float4*)anchors)[a];
        float ax1 = cf.x - cf.z * 0.5f, ay1 = cf.y - cf.w * 0.5f;
        float ax2 = cf.x + cf.z * 0.5f, ay2 = cf.y + cf.w * 0.5f;
        float aarea = (ax2 - ax1) * (ay2 - ay1);
        float best = -1.0f; int bm = 0;
        #pragma unroll
        for (int m = 0; m < NM; m++) {
            if (m < cnt) {
                float ltx = fmaxf(sg[m][0], ax1), lty = fmaxf(sg[m][1], ay1);
                float rbx = fminf(sg[m][2], ax2), rby = fminf(sg[m][3], ay2);
                float wx = fmaxf(rbx - ltx, 0.0f), wy = fmaxf(rby - lty, 0.0f);
                float inter = wx * wy;
                float iou = inter / (sg[m][4] + aarea - inter + 1e-10f);  // IEEE div: threshold-exact vs ref
                if (iou > best) { best = iou; bm = m; }   // strict >: first m wins ties
                unsigned long long k = packKey(iou, (unsigned)a);
                if (k > bp[m]) bp[m] = k;
            }
        }
        bt_iou[(size_t)bs * NA + a] = best;
        bt_idx[(size_t)bs * NA + a] = bm;
    }

    // per-wave shfl max, cross-wave via LDS, plain store to this block's chunk slots
    __shared__ unsigned long long sk[4][NM];
    int wave = t >> 6, lane = t & 63;
    for (int m = 0; m < cnt; m++) {       // cnt is block-uniform
        unsigned long long k = bp[m];
        #pragma unroll
        for (int off = 32; off > 0; off >>= 1) {
            unsigned long long o = __shfl_xor(k, off);
            if (o > k) k = o;
        }
        if (lane == 0) sk[wave][m] = k;
    }
    __syncthreads();
    if (t < NM) {
        unsigned long long k = 0ULL;
        if (t < cnt) {
            k = sk[0][t];
            if (sk[1][t] > k) k = sk[1][t];
            if (sk[2][t] > k) k = sk[2][t];
            if (sk[3][t] > k) k = sk[3][t];
        }
        chunkbest[bid * NM + t] = k;      // write all NM slots (ws is poisoned)
    }
}

// ---------------- kernel 2: fused match + regression + full cls loss ----------------
// Per anchor: resolve force-match (scan <=cnt per-gt best anchors, ascending ==
// last-write-wins numpy scatter), then directly accumulate this anchor's 80-class
// focal term reading its logits row once. Ignore-band anchors skip the row entirely.
// Identities (e=exp(-x), s=1+e, p=1/s): -log(p)=log(s), -log(1-p)=x+log(s), 1-p=e*p.
__global__ void __launch_bounds__(256)
k_match(const float* __restrict__ gtb, const int* __restrict__ counts,
        const float* __restrict__ anchors, const float* __restrict__ ploc,
        const float* __restrict__ gtl, const float* __restrict__ logits,
        const int* __restrict__ cls_num,
        const unsigned long long* __restrict__ chunkbest,
        const float* __restrict__ bt_iou, const int* __restrict__ bt_idx,
        double* __restrict__ acc, int* __restrict__ npos) {
    int bid = blockIdx.x;
    int bs = bid / CPB;
    int chunk = bid % CPB;
    int t = threadIdx.x;
    int cnt = counts[bs];

    __shared__ float sg[NM][4];
    __shared__ unsigned abest[NM];
    __shared__ float wsh[NC];
    __shared__ float wsum_sh;
    if (t < NM) {
        const float* g = gtb + ((size_t)bs * NM + t) * 4;
        sg[t][0] = g[0]; sg[t][1] = g[1]; sg[t][2] = g[2]; sg[t][3] = g[3];
    }
    // CB weights, computed redundantly per block (80 powf — negligible)
    if (t < NC) {
        float n = (float)cls_num[t];
        wsh[t] = OMB / (1.0f - powf(0.9999f, n));   // numerator cancels in normalization
    }
    // per-gt global best anchor: reduce over the CPB chunk slots
    if (t < NM && t < cnt) {
        unsigned long long k = 0ULL;
        for (int c = 0; c < CPB; c++) {
            unsigned long long o = chunkbest[(bs * CPB + c) * NM + t];
            if (o > k) k = o;
        }
        abest[t] = 0xFFFFFFFFu - (unsigned)(k & 0xFFFFFFFFull);
    }
    __syncthreads();
    if (t == 0) {
        float s = 0.0f;
        for (int c = 0; c < NC; c++) s += wsh[c];
        wsum_sh = s;
    }
    __syncthreads();
    if (t < NC) wsh[t] = wsh[t] / wsum_sh;
    __syncthreads();

    const float SL1B = 1.0f / 9.0f;
    float regsum = 0.0f, possum = 0.0f, bgsum = 0.0f;
    int pcnt = 0;
    int a0 = chunk * APC;
    for (int a = a0 + t; a < a0 + APC; a += 256) {
        size_t ia = (size_t)bs * NA + a;
        float iou = bt_iou[ia];
        int idx = bt_idx[ia];
        for (int m = 0; m < cnt; m++) {           // ascending: last match wins
            if (abest[m] == (unsigned)a) { iou = 2.0f; idx = m; }
        }
        int code;
        if (cnt == 0) code = -1;
        else if (iou < NEG_TH) code = 0;
        else if (iou < POS_TH) code = -1;
        else code = idx + 1;

        if (code == 0) {
            // background anchor: all 80 classes y==0
            const float4* xrow = (const float4*)(logits + ia * NC);
            #pragma unroll 5
            for (int c4 = 0; c4 < NC / 4; c4++) {
                float4 x4 = xrow[c4];
                float xv[4] = {x4.x, x4.y, x4.z, x4.w};
                #pragma unroll
                for (int j = 0; j < 4; j++) {
                    float x = xv[j];
                    float e = __expf(-x);
                    float s = 1.0f + e;
                    float pr = __builtin_amdgcn_rcpf(s);
                    float ls = __logf(s);
                    bgsum += (x + ls) * pr;
                }
            }
        } else if (code > 0) {
            pcnt++;
            // regression (smooth-L1 on SSD-encoded offsets)
            float4 cf = ((const float4*)anchors)[a];
            float mx1 = sg[idx][0], my1 = sg[idx][1], mx2 = sg[idx][2], my2 = sg[idx][3];
            float g0 = ((mx1 + mx2) * 0.5f - cf.x) / (0.1f * cf.z);
            float g1 = ((my1 + my2) * 0.5f - cf.y) / (0.1f * cf.w);
            float g2 = logf(fmaxf(mx2 - mx1, 1e-6f) / cf.z) / 0.2f;
            float g3 = logf(fmaxf(my2 - my1, 1e-6f) / cf.w) / 0.2f;
            float4 p = ((const float4*)ploc)[ia];
            float n0 = fabsf(p.x - g0), n1 = fabsf(p.y - g1);
            float n2 = fabsf(p.z - g2), n3 = fabsf(p.w - g3);
            float s0 = n0 < SL1B ? 0.5f * n0 * n0 / SL1B : n0 - 0.5f * SL1B;
            float s1 = n1 < SL1B ? 0.5f * n1 * n1 / SL1B : n1 - 0.5f * SL1B;
            float s2 = n2 < SL1B ? 0.5f * n2 * n2 / SL1B : n2 - 0.5f * SL1B;
            float s3 = n3 < SL1B ? 0.5f * n3 * n3 / SL1B : n3 - 0.5f * SL1B;
            regsum += s0 + s1 + s2 + s3;

            // full 80-class focal term with this anchor's multi-hot gt row
            const float4* yrow = (const float4*)(gtl + ((size_t)(bs * NM + idx)) * NC);
            const float4* xrow = (const float4*)(logits + ia * NC);
            #pragma unroll 5
            for (int c4 = 0; c4 < NC / 4; c4++) {
                float4 y4 = yrow[c4];
                float4 x4 = xrow[c4];
                float yv[4] = {y4.x, y4.y, y4.z, y4.w};
                float xv[4] = {x4.x, x4.y, x4.z, x4.w};
                #pragma unroll
                for (int j = 0; j < 4; j++) {
                    float x = xv[j];
                    float e = __expf(-x);
                    float s = 1.0f + e;
                    float pr = __builtin_amdgcn_rcpf(s);
                    float ls = __logf(s);
                    if (yv[j] > 0.5f) possum += ls * wsh[c4 * 4 + j] * (e * pr);
                    else              bgsum += (x + ls) * pr;
                }
            }
        }
        // code == -1 (ignore): contributes nothing, logits row never read
    }
    float clssum = possum + OMB * bgsum;

    // wave shfl-reduce then cross-wave LDS then one atomic per block
    #pragma unroll
    for (int off = 32; off > 0; off >>= 1) {
        regsum += __shfl_xor(regsum, off);
        clssum += __shfl_xor(clssum, off);
        pcnt   += __shfl_xor(pcnt, off);
    }
    __shared__ float sf[4], sc[4];
    __shared__ int   si[4];
    int wave = t >> 6, lane = t & 63;
    if (lane == 0) { sf[wave] = regsum; sc[wave] = clssum; si[wave] = pcnt; }
    __syncthreads();
    if (t == 0) {
        atomicAdd(&acc[0], (double)(sf[0] + sf[1] + sf[2] + sf[3]));
        atomicAdd(&acc[1], (double)(sc[0] + sc[1] + sc[2] + sc[3]));
        atomicAdd(npos, si[0] + si[1] + si[2] + si[3]);
    }
}

// ---------------- kernel 3: ego focal loss + final combine ----------------
__global__ void k_final(const float* __restrict__ ego_preds, const int* __restrict__ ego_labels,
                        const double* __restrict__ acc, const int* __restrict__ npos,
                        float* __restrict__ out) {
    __shared__ float scol[NCE];
    __shared__ float sred[128];
    __shared__ int   sval[128];
    const float EPSF = 1e-7f;
    int t = threadIdx.x;
    if (t < NCE) {
        float c = 0.0f;
        for (int i = 0; i < NBS; i++) {
            int l = ego_labels[i];
            if (l > -1 && l == t) c = 1.0f;
        }
        scol[t] = c;
    }
    __syncthreads();

    float term = 0.0f;
    if (t < NBS * NCE) {
        int bs = t / NCE, e = t % NCE;
        int lbl = ego_labels[bs];
        if (lbl > -1) {
            float x = ego_preds[t];
            float ep = 1.0f / (1.0f + expf(-x));
            float oh = scol[e];
            float af = 0.25f * oh + 0.75f * (1.0f - oh);
            float ept = ep * oh + (1.0f - ep) * (1.0f - oh);
            float epc = fminf(fmaxf(ep, EPSF), 1.0f - EPSF);
            float bce = -(oh * logf(epc) + (1.0f - oh) * log1pf(-epc));
            float om = 1.0f - ept;
            term = bce * af * om * om;
        }
    }
    sred[t] = term;
    sval[t] = (t < NBS && ego_labels[t] > -1) ? 1 : 0;
    __syncthreads();
    for (int off = 64; off > 0; off >>= 1) {
        if (t < off) { sred[t] += sred[t + off]; sval[t] += sval[t + off]; }
        __syncthreads();
    }
    if (t == 0) {
        float esum = sred[0];
        int ne = sval[0];
        float ego = (ne > 0) ? esum / (float)(ne > 1 ? ne : 1) : 0.0f;
        double npd = (double)(*npos);
        if (npd < 1.0) npd = 1.0;
        out[0] = (float)(acc[0] / (npd * 4.0));
        out[1] = (float)(acc[1] / npd / 8.0 + (double)ego / 4.0);
    }
}

// ---------------- host launch ----------------
extern "C" void kernel_launch(void* const* d_in, const int* in_sizes, int n_in,
                              void* d_out, int out_size, void* d_ws, size_t ws_size,
                              hipStream_t stream) {
    const float* confidence = (const float*)d_in[0];
    const float* ploc       = (const float*)d_in[1];
    const float* gtb        = (const float*)d_in[2];
    const float* gtl        = (const float*)d_in[3];
    const int*   counts     = (const int*)d_in[4];
    const float* anchors    = (const float*)d_in[5];
    const float* ego_preds  = (const float*)d_in[6];
    const int*   ego_labels = (const int*)d_in[7];
    const int*   cls_num    = (const int*)d_in[8];
    float* out = (float*)d_out;

    // workspace layout (16B aligned chunks)
    char* ws = (char*)d_ws;
    double* acc  = (double*)ws;                               // [0]=reg_sum, [1]=cls_sum
    int* npos    = (int*)(ws + 16);
    unsigned long long* chunkbest = (unsigned long long*)(ws + 64);   // 1024*20 u64 = 160 KB
    float* bt_iou = (float*)(ws + 64 + 163840);               // 16*24000 f32
    int*   bt_idx = (int*)(ws + 64 + 163840 + 1536000);       // 16*24000 i32

    k_iou<<<NBS * CPB, 256, 0, stream>>>(gtb, counts, anchors, bt_iou, bt_idx,
                                         chunkbest, acc, npos);
    k_match<<<NBS * CPB, 256, 0, stream>>>(gtb, counts, anchors, ploc, gtl, confidence,
                                           cls_num, chunkbest, bt_iou, bt_idx, acc, npos);
    k_final<<<1, 128, 0, stream>>>(ego_preds, ego_labels, acc, npos, out);
}

// Round 7
// 274.322 us; speedup vs baseline: 1.4683x; 1.0357x over previous
//
#include <hip/hip_runtime.h>
#include <math.h>

// Problem constants (match reference)
#define NB 2
#define NS 8
#define NA 24000
#define NC 80
#define NM 20
#define NCE 7
#define NBS (NB*NS)          // 16 frames
#define CPB 64               // chunks (blocks) per frame
#define APC (NA/CPB)         // anchors per chunk = 375
#define F4PC (APC*NC/4)      // float4s per chunk = 7500

#define POS_TH 0.5f
#define NEG_TH 0.4f
#define OMB 1e-4f            // 1.0 - 0.9999 (correctly rounded to f32)

// pack (iou, anchor_idx) into u64 so that max-reduce picks higher iou,
// tie -> smaller anchor index (argmax first-occurrence semantics)
__device__ inline unsigned long long packKey(float f, unsigned idx) {
    unsigned u = __float_as_uint(f);
    u = (u & 0x80000000u) ? ~u : (u | 0x80000000u);   // total order on floats
    return ((unsigned long long)u << 32) | (unsigned long long)(0xFFFFFFFFu - idx);
}

// ---------------- kernel 1: IoU, per-anchor best gt, per-(gt,chunk) best anchor -------
__global__ void __launch_bounds__(256)
k_iou(const float* __restrict__ gtb, const int* __restrict__ counts,
      const float* __restrict__ anchors,
      float* __restrict__ bt_iou, int* __restrict__ bt_idx,
      unsigned long long* __restrict__ chunkbest,
      double* __restrict__ acc, int* __restrict__ npos) {
    int bid = blockIdx.x;
    int bs = bid / CPB;
    int chunk = bid % CPB;
    int t = threadIdx.x;
    int cnt = counts[bs];

    if (bid == 0 && t == 0) { acc[0] = 0.0; acc[1] = 0.0; *npos = 0; }

    __shared__ float sg[NM][5];   // x1,y1,x2,y2,area (gt already point form)
    if (t < NM) {
        const float* g = gtb + ((size_t)bs * NM + t) * 4;
        float x1 = g[0], y1 = g[1], x2 = g[2], y2 = g[3];
        sg[t][0] = x1; sg[t][1] = y1; sg[t][2] = x2; sg[t][3] = y2;
        sg[t][4] = (x2 - x1) * (y2 - y1);
    }
    __syncthreads();

    unsigned long long bp[NM];
    #pragma unroll
    for (int m = 0; m < NM; m++) bp[m] = 0ULL;

    int a0 = chunk * APC;
    for (int a = a0 + t; a < a0 + APC; a += 256) {
        float4 cf = ((const float4*)anchors)[a];
        float ax1 = cf.x - cf.z * 0.5f, ay1 = cf.y - cf.w * 0.5f;
        float ax2 = cf.x + cf.z * 0.5f, ay2 = cf.y + cf.w * 0.5f;
        float aarea = (ax2 - ax1) * (ay2 - ay1);
        float best = -1.0f; int bm = 0;
        #pragma unroll
        for (int m = 0; m < NM; m++) {
            if (m < cnt) {
                float ltx = fmaxf(sg[m][0], ax1), lty = fmaxf(sg[m][1], ay1);
                float rbx = fminf(sg[m][2], ax2), rby = fminf(sg[m][3], ay2);
                float wx = fmaxf(rbx - ltx, 0.0f), wy = fmaxf(rby - lty, 0.0f);
                float inter = wx * wy;
                float iou = inter / (sg[m][4] + aarea - inter + 1e-10f);  // IEEE div: threshold-exact vs ref
                if (iou > best) { best = iou; bm = m; }   // strict >: first m wins ties
                unsigned long long k = packKey(iou, (unsigned)a);
                if (k > bp[m]) bp[m] = k;
            }
        }
        bt_iou[(size_t)bs * NA + a] = best;
        bt_idx[(size_t)bs * NA + a] = bm;
    }

    // per-wave shfl max, cross-wave via LDS, plain store to this block's chunk slots
    __shared__ unsigned long long sk[4][NM];
    int wave = t >> 6, lane = t & 63;
    for (int m = 0; m < cnt; m++) {       // cnt is block-uniform
        unsigned long long k = bp[m];
        #pragma unroll
        for (int off = 32; off > 0; off >>= 1) {
            unsigned long long o = __shfl_xor(k, off);
            if (o > k) k = o;
        }
        if (lane == 0) sk[wave][m] = k;
    }
    __syncthreads();
    if (t < NM) {
        unsigned long long k = 0ULL;
        if (t < cnt) {
            k = sk[0][t];
            if (sk[1][t] > k) k = sk[1][t];
            if (sk[2][t] > k) k = sk[2][t];
            if (sk[3][t] > k) k = sk[3][t];
        }
        chunkbest[bid * NM + t] = k;      // write all NM slots (ws is poisoned)
    }
}

// ---------------- kernel 2: fused match + regression + cls loss (coalesced) ----------
// Phase A (per anchor): resolve force-match, conf code -> LDS, regression loss.
// Phase B (streaming): block sweeps its CONTIGUOUS logits region lane->float4
// consecutive (fully coalesced); code/idx looked up from LDS.
// Identities (e=exp(-x), s=1+e, p=1/s): -log(p)=log(s), -log(1-p)=x+log(s), 1-p=e*p.
__global__ void __launch_bounds__(256)
k_match(const float* __restrict__ gtb, const int* __restrict__ counts,
        const float* __restrict__ anchors, const float* __restrict__ ploc,
        const float* __restrict__ gtl, const float* __restrict__ logits,
        const int* __restrict__ cls_num,
        const unsigned long long* __restrict__ chunkbest,
        const float* __restrict__ bt_iou, const int* __restrict__ bt_idx,
        double* __restrict__ acc, int* __restrict__ npos) {
    int bid = blockIdx.x;
    int bs = bid / CPB;
    int chunk = bid % CPB;
    int t = threadIdx.x;
    int cnt = counts[bs];

    __shared__ float sg[NM][4];
    __shared__ unsigned abest[NM];
    __shared__ float wsh[NC];
    __shared__ float wsum_sh;
    __shared__ int scode[APC];     // per-anchor conf code (this chunk)
    __shared__ int sidx[APC];      // per-anchor matched gt
    if (t < NM) {
        const float* g = gtb + ((size_t)bs * NM + t) * 4;
        sg[t][0] = g[0]; sg[t][1] = g[1]; sg[t][2] = g[2]; sg[t][3] = g[3];
    }
    // CB weights, computed redundantly per block (80 powf — negligible)
    if (t < NC) {
        float n = (float)cls_num[t];
        wsh[t] = OMB / (1.0f - powf(0.9999f, n));   // numerator cancels in normalization
    }
    // per-gt global best anchor: reduce over the CPB chunk slots
    if (t < NM && t < cnt) {
        unsigned long long k = 0ULL;
        for (int c = 0; c < CPB; c++) {
            unsigned long long o = chunkbest[(bs * CPB + c) * NM + t];
            if (o > k) k = o;
        }
        abest[t] = 0xFFFFFFFFu - (unsigned)(k & 0xFFFFFFFFull);
    }
    __syncthreads();
    if (t == 0) {
        float s = 0.0f;
        for (int c = 0; c < NC; c++) s += wsh[c];
        wsum_sh = s;
    }
    __syncthreads();
    if (t < NC) wsh[t] = wsh[t] / wsum_sh;

    // ---------------- phase A: codes + regression ----------------
    const float SL1B = 1.0f / 9.0f;
    float regsum = 0.0f;
    int pcnt = 0;
    int a0 = chunk * APC;
    for (int al = t; al < APC; al += 256) {
        int a = a0 + al;
        size_t ia = (size_t)bs * NA + a;
        float iou = bt_iou[ia];
        int idx = bt_idx[ia];
        for (int m = 0; m < cnt; m++) {           // ascending: last match wins
            if (abest[m] == (unsigned)a) { iou = 2.0f; idx = m; }
        }
        int code;
        if (cnt == 0) code = -1;
        else if (iou < NEG_TH) code = 0;
        else if (iou < POS_TH) code = -1;
        else code = idx + 1;
        scode[al] = code;
        sidx[al] = idx;
        if (code > 0) {
            pcnt++;
            float4 cf = ((const float4*)anchors)[a];
            float mx1 = sg[idx][0], my1 = sg[idx][1], mx2 = sg[idx][2], my2 = sg[idx][3];
            float g0 = ((mx1 + mx2) * 0.5f - cf.x) / (0.1f * cf.z);
            float g1 = ((my1 + my2) * 0.5f - cf.y) / (0.1f * cf.w);
            float g2 = logf(fmaxf(mx2 - mx1, 1e-6f) / cf.z) / 0.2f;
            float g3 = logf(fmaxf(my2 - my1, 1e-6f) / cf.w) / 0.2f;
            float4 p = ((const float4*)ploc)[ia];
            float n0 = fabsf(p.x - g0), n1 = fabsf(p.y - g1);
            float n2 = fabsf(p.z - g2), n3 = fabsf(p.w - g3);
            float s0 = n0 < SL1B ? 0.5f * n0 * n0 / SL1B : n0 - 0.5f * SL1B;
            float s1 = n1 < SL1B ? 0.5f * n1 * n1 / SL1B : n1 - 0.5f * SL1B;
            float s2 = n2 < SL1B ? 0.5f * n2 * n2 / SL1B : n2 - 0.5f * SL1B;
            float s3 = n3 < SL1B ? 0.5f * n3 * n3 / SL1B : n3 - 0.5f * SL1B;
            regsum += s0 + s1 + s2 + s3;
        }
    }
    __syncthreads();

    // ---------------- phase B: coalesced streaming over this block's logits ----------
    const float4* x4p = (const float4*)logits;
    const float4* y4p = (const float4*)gtl;
    size_t base4 = ((size_t)bs * NA + a0) * (NC / 4);
    float possum = 0.0f, bgsum = 0.0f;
    for (int i = t; i < F4PC; i += 256) {
        int al = i / 20;               // local anchor
        int code = scode[al];
        if (code == -1) continue;
        float4 x4 = x4p[base4 + i];
        float xv[4] = {x4.x, x4.y, x4.z, x4.w};
        if (code > 0) {
            int c4 = i - al * 20;
            int idx = sidx[al];
            float4 y4 = y4p[(bs * NM + idx) * 20 + c4];
            float yv[4] = {y4.x, y4.y, y4.z, y4.w};
            #pragma unroll
            for (int j = 0; j < 4; j++) {
                float x = xv[j];
                float e = __expf(-x);
                float s = 1.0f + e;
                float pr = __builtin_amdgcn_rcpf(s);
                float ls = __logf(s);
                if (yv[j] > 0.5f) possum += ls * wsh[c4 * 4 + j] * (e * pr);
                else              bgsum += (x + ls) * pr;
            }
        } else {
            #pragma unroll
            for (int j = 0; j < 4; j++) {
                float x = xv[j];
                float e = __expf(-x);
                float s = 1.0f + e;
                float pr = __builtin_amdgcn_rcpf(s);
                float ls = __logf(s);
                bgsum += (x + ls) * pr;
            }
        }
    }
    float clssum = possum + OMB * bgsum;

    // wave shfl-reduce then cross-wave LDS then one atomic per block
    #pragma unroll
    for (int off = 32; off > 0; off >>= 1) {
        regsum += __shfl_xor(regsum, off);
        clssum += __shfl_xor(clssum, off);
        pcnt   += __shfl_xor(pcnt, off);
    }
    __shared__ float sf[4], sc[4];
    __shared__ int   si[4];
    int wave = t >> 6, lane = t & 63;
    if (lane == 0) { sf[wave] = regsum; sc[wave] = clssum; si[wave] = pcnt; }
    __syncthreads();
    if (t == 0) {
        atomicAdd(&acc[0], (double)(sf[0] + sf[1] + sf[2] + sf[3]));
        atomicAdd(&acc[1], (double)(sc[0] + sc[1] + sc[2] + sc[3]));
        atomicAdd(npos, si[0] + si[1] + si[2] + si[3]);
    }
}

// ---------------- kernel 3: ego focal loss + final combine ----------------
__global__ void k_final(const float* __restrict__ ego_preds, const int* __restrict__ ego_labels,
                        const double* __restrict__ acc, const int* __restrict__ npos,
                        float* __restrict__ out) {
    __shared__ float scol[NCE];
    __shared__ float sred[128];
    __shared__ int   sval[128];
    const float EPSF = 1e-7f;
    int t = threadIdx.x;
    if (t < NCE) {
        float c = 0.0f;
        for (int i = 0; i < NBS; i++) {
            int l = ego_labels[i];
            if (l > -1 && l == t) c = 1.0f;
        }
        scol[t] = c;
    }
    __syncthreads();

    float term = 0.0f;
    if (t < NBS * NCE) {
        int bs = t / NCE, e = t % NCE;
        int lbl = ego_labels[bs];
        if (lbl > -1) {
            float x = ego_preds[t];
            float ep = 1.0f / (1.0f + expf(-x));
            float oh = scol[e];
            float af = 0.25f * oh + 0.75f * (1.0f - oh);
            float ept = ep * oh + (1.0f - ep) * (1.0f - oh);
            float epc = fminf(fmaxf(ep, EPSF), 1.0f - EPSF);
            float bce = -(oh * logf(epc) + (1.0f - oh) * log1pf(-epc));
            float om = 1.0f - ept;
            term = bce * af * om * om;
        }
    }
    sred[t] = term;
    sval[t] = (t < NBS && ego_labels[t] > -1) ? 1 : 0;
    __syncthreads();
    for (int off = 64; off > 0; off >>= 1) {
        if (t < off) { sred[t] += sred[t + off]; sval[t] += sval[t + off]; }
        __syncthreads();
    }
    if (t == 0) {
        float esum = sred[0];
        int ne = sval[0];
        float ego = (ne > 0) ? esum / (float)(ne > 1 ? ne : 1) : 0.0f;
        double npd = (double)(*npos);
        if (npd < 1.0) npd = 1.0;
        out[0] = (float)(acc[0] / (npd * 4.0));
        out[1] = (float)(acc[1] / npd / 8.0 + (double)ego / 4.0);
    }
}

// ---------------- host launch ----------------
extern "C" void kernel_launch(void* const* d_in, const int* in_sizes, int n_in,
                              void* d_out, int out_size, void* d_ws, size_t ws_size,
                              hipStream_t stream) {
    const float* confidence = (const float*)d_in[0];
    const float* ploc       = (const float*)d_in[1];
    const float* gtb        = (const float*)d_in[2];
    const float* gtl        = (const float*)d_in[3];
    const int*   counts     = (const int*)d_in[4];
    const float* anchors    = (const float*)d_in[5];
    const float* ego_preds  = (const float*)d_in[6];
    const int*   ego_labels = (const int*)d_in[7];
    const int*   cls_num    = (const int*)d_in[8];
    float* out = (float*)d_out;

    // workspace layout (16B aligned chunks)
    char* ws = (char*)d_ws;
    double* acc  = (double*)ws;                               // [0]=reg_sum, [1]=cls_sum
    int* npos    = (int*)(ws + 16);
    unsigned long long* chunkbest = (unsigned long long*)(ws + 64);   // 1024*20 u64 = 160 KB
    float* bt_iou = (float*)(ws + 64 + 163840);               // 16*24000 f32
    int*   bt_idx = (int*)(ws + 64 + 163840 + 1536000);       // 16*24000 i32

    k_iou<<<NBS * CPB, 256, 0, stream>>>(gtb, counts, anchors, bt_iou, bt_idx,
                                         chunkbest, acc, npos);
    k_match<<<NBS * CPB, 256, 0, stream>>>(gtb, counts, anchors, ploc, gtl, confidence,
                                           cls_num, chunkbest, bt_iou, bt_idx, acc, npos);
    k_final<<<1, 128, 0, stream>>>(ego_preds, ego_labels, acc, npos, out);
}

// Round 8
// 270.664 us; speedup vs baseline: 1.4881x; 1.0135x over previous
//
#include <hip/hip_runtime.h>
#include <math.h>

// Problem constants (match reference)
#define NB 2
#define NS 8
#define NA 24000
#define NC 80
#define NM 20
#define NCE 7
#define NBS (NB*NS)          // 16 frames
#define CPB 75               // chunks (blocks) per frame
#define APC (NA/CPB)         // anchors per chunk = 320
#define F4PC (APC*NC/4)      // float4s per chunk = 6400 = 25*256 exactly

#define POS_TH 0.5f
#define NEG_TH 0.4f
#define OMB 1e-4f            // 1.0 - 0.9999 (correctly rounded to f32)

// pack (iou, anchor_idx) into u64 so that max-reduce picks higher iou,
// tie -> smaller anchor index (argmax first-occurrence semantics)
__device__ inline unsigned long long packKey(float f, unsigned idx) {
    unsigned u = __float_as_uint(f);
    u = (u & 0x80000000u) ? ~u : (u | 0x80000000u);   // total order on floats
    return ((unsigned long long)u << 32) | (unsigned long long)(0xFFFFFFFFu - idx);
}

// ---------------- kernel 1: IoU, per-anchor best gt, per-(gt,chunk) best anchor -------
__global__ void __launch_bounds__(256)
k_iou(const float* __restrict__ gtb, const int* __restrict__ counts,
      const float* __restrict__ anchors,
      float* __restrict__ bt_iou, int* __restrict__ bt_idx,
      unsigned long long* __restrict__ chunkbest,
      double* __restrict__ acc, int* __restrict__ npos) {
    int bid = blockIdx.x;
    int bs = bid / CPB;
    int chunk = bid % CPB;
    int t = threadIdx.x;
    int cnt = counts[bs];

    if (bid == 0 && t == 0) { acc[0] = 0.0; acc[1] = 0.0; *npos = 0; }

    __shared__ float sg[NM][5];   // x1,y1,x2,y2,area (gt already point form)
    if (t < NM) {
        const float* g = gtb + ((size_t)bs * NM + t) * 4;
        float x1 = g[0], y1 = g[1], x2 = g[2], y2 = g[3];
        sg[t][0] = x1; sg[t][1] = y1; sg[t][2] = x2; sg[t][3] = y2;
        sg[t][4] = (x2 - x1) * (y2 - y1);
    }
    __syncthreads();

    unsigned long long bp[NM];
    #pragma unroll
    for (int m = 0; m < NM; m++) bp[m] = 0ULL;

    int a0 = chunk * APC;
    for (int a = a0 + t; a < a0 + APC; a += 256) {
        float4 cf = ((const float4*)anchors)[a];
        float ax1 = cf.x - cf.z * 0.5f, ay1 = cf.y - cf.w * 0.5f;
        float ax2 = cf.x + cf.z * 0.5f, ay2 = cf.y + cf.w * 0.5f;
        float aarea = (ax2 - ax1) * (ay2 - ay1);
        float best = -1.0f; int bm = 0;
        #pragma unroll
        for (int m = 0; m < NM; m++) {
            if (m < cnt) {
                float ltx = fmaxf(sg[m][0], ax1), lty = fmaxf(sg[m][1], ay1);
                float rbx = fminf(sg[m][2], ax2), rby = fminf(sg[m][3], ay2);
                float wx = fmaxf(rbx - ltx, 0.0f), wy = fmaxf(rby - lty, 0.0f);
                float inter = wx * wy;
                float iou = inter / (sg[m][4] + aarea - inter + 1e-10f);  // IEEE div: threshold-exact vs ref
                if (iou > best) { best = iou; bm = m; }   // strict >: first m wins ties
                unsigned long long k = packKey(iou, (unsigned)a);
                if (k > bp[m]) bp[m] = k;
            }
        }
        bt_iou[(size_t)bs * NA + a] = best;
        bt_idx[(size_t)bs * NA + a] = bm;
    }

    // per-wave shfl max, cross-wave via LDS, plain store to this block's chunk slots
    __shared__ unsigned long long sk[4][NM];
    int wave = t >> 6, lane = t & 63;
    for (int m = 0; m < cnt; m++) {       // cnt is block-uniform
        unsigned long long k = bp[m];
        #pragma unroll
        for (int off = 32; off > 0; off >>= 1) {
            unsigned long long o = __shfl_xor(k, off);
            if (o > k) k = o;
        }
        if (lane == 0) sk[wave][m] = k;
    }
    __syncthreads();
    if (t < NM) {
        unsigned long long k = 0ULL;
        if (t < cnt) {
            k = sk[0][t];
            if (sk[1][t] > k) k = sk[1][t];
            if (sk[2][t] > k) k = sk[2][t];
            if (sk[3][t] > k) k = sk[3][t];
        }
        chunkbest[bid * NM + t] = k;      // write all NM slots (ws is poisoned)
    }
}

// ---------------- kernel 2: fused match + regression + cls loss ----------------
// Phase A (per anchor): resolve force-match, mask -> LDS, regression loss, and the
// pos-anchor class correction: corr = sum_{y==1}[ w*ls*(e*p) - OMB*(x+ls)*p ].
// Phase B (streaming): branch-free mask-FMA over this block's CONTIGUOUS logits
// region, batch-5 register staging (masks from LDS) => ~10 loads in flight/thread.
// Identities (e=exp(-x), s=1+e, p=1/s): -log(p)=log(s), -log(1-p)=x+log(s), 1-p=e*p.
__global__ void __launch_bounds__(256)
k_match(const float* __restrict__ gtb, const int* __restrict__ counts,
        const float* __restrict__ anchors, const float* __restrict__ ploc,
        const float* __restrict__ gtl, const float* __restrict__ logits,
        const int* __restrict__ cls_num,
        const unsigned long long* __restrict__ chunkbest,
        const float* __restrict__ bt_iou, const int* __restrict__ bt_idx,
        double* __restrict__ acc, int* __restrict__ npos) {
    int bid = blockIdx.x;
    int bs = bid / CPB;
    int chunk = bid % CPB;
    int t = threadIdx.x;
    int cnt = counts[bs];

    __shared__ float sg[NM][4];
    __shared__ unsigned abest[NM];
    __shared__ float wsh[NC];
    __shared__ float wsum_sh;
    __shared__ float smask[APC];   // per-anchor cmask (0 = ignore, 1 = contributes)
    if (t < NM) {
        const float* g = gtb + ((size_t)bs * NM + t) * 4;
        sg[t][0] = g[0]; sg[t][1] = g[1]; sg[t][2] = g[2]; sg[t][3] = g[3];
    }
    // CB weights, computed redundantly per block (80 powf — negligible)
    if (t < NC) {
        float n = (float)cls_num[t];
        wsh[t] = OMB / (1.0f - powf(0.9999f, n));   // numerator cancels in normalization
    }
    // per-gt global best anchor: reduce over the CPB chunk slots
    if (t < NM && t < cnt) {
        unsigned long long k = 0ULL;
        for (int c = 0; c < CPB; c++) {
            unsigned long long o = chunkbest[(bs * CPB + c) * NM + t];
            if (o > k) k = o;
        }
        abest[t] = 0xFFFFFFFFu - (unsigned)(k & 0xFFFFFFFFull);
    }
    __syncthreads();
    if (t == 0) {
        float s = 0.0f;
        for (int c = 0; c < NC; c++) s += wsh[c];
        wsum_sh = s;
    }
    __syncthreads();
    if (t < NC) wsh[t] = wsh[t] / wsum_sh;

    // ---------------- phase A: codes + regression + pos correction ----------------
    const float SL1B = 1.0f / 9.0f;
    float regsum = 0.0f, corrsum = 0.0f;
    int pcnt = 0;
    int a0 = chunk * APC;
    for (int al = t; al < APC; al += 256) {
        int a = a0 + al;
        size_t ia = (size_t)bs * NA + a;
        float iou = bt_iou[ia];
        int idx = bt_idx[ia];
        for (int m = 0; m < cnt; m++) {           // ascending: last match wins
            if (abest[m] == (unsigned)a) { iou = 2.0f; idx = m; }
        }
        int code;
        if (cnt == 0) code = -1;
        else if (iou < NEG_TH) code = 0;
        else if (iou < POS_TH) code = -1;
        else code = idx + 1;
        smask[al] = (code == -1) ? 0.0f : 1.0f;
        if (code > 0) {
            pcnt++;
            float4 cf = ((const float4*)anchors)[a];
            float mx1 = sg[idx][0], my1 = sg[idx][1], mx2 = sg[idx][2], my2 = sg[idx][3];
            float g0 = ((mx1 + mx2) * 0.5f - cf.x) / (0.1f * cf.z);
            float g1 = ((my1 + my2) * 0.5f - cf.y) / (0.1f * cf.w);
            float g2 = logf(fmaxf(mx2 - mx1, 1e-6f) / cf.z) / 0.2f;
            float g3 = logf(fmaxf(my2 - my1, 1e-6f) / cf.w) / 0.2f;
            float4 p = ((const float4*)ploc)[ia];
            float n0 = fabsf(p.x - g0), n1 = fabsf(p.y - g1);
            float n2 = fabsf(p.z - g2), n3 = fabsf(p.w - g3);
            float s0 = n0 < SL1B ? 0.5f * n0 * n0 / SL1B : n0 - 0.5f * SL1B;
            float s1 = n1 < SL1B ? 0.5f * n1 * n1 / SL1B : n1 - 0.5f * SL1B;
            float s2 = n2 < SL1B ? 0.5f * n2 * n2 / SL1B : n2 - 0.5f * SL1B;
            float s3 = n3 < SL1B ? 0.5f * n3 * n3 / SL1B : n3 - 0.5f * SL1B;
            regsum += s0 + s1 + s2 + s3;

            // pos-class correction over this anchor's y==1 classes (rare, ~4/80)
            const float4* yrow = (const float4*)(gtl + ((size_t)(bs * NM + idx)) * NC);
            const float4* xrow = (const float4*)(logits + ia * NC);
            #pragma unroll 4
            for (int c4 = 0; c4 < NC / 4; c4++) {
                float4 y4 = yrow[c4];
                if (y4.x > 0.5f || y4.y > 0.5f || y4.z > 0.5f || y4.w > 0.5f) {
                    float4 x4 = xrow[c4];
                    float yv[4] = {y4.x, y4.y, y4.z, y4.w};
                    float xv[4] = {x4.x, x4.y, x4.z, x4.w};
                    #pragma unroll
                    for (int j = 0; j < 4; j++) {
                        if (yv[j] > 0.5f) {
                            float x = xv[j];
                            float e = __expf(-x);
                            float s = 1.0f + e;
                            float pr = __builtin_amdgcn_rcpf(s);
                            float ls = __logf(s);
                            corrsum += ls * wsh[c4 * 4 + j] * (e * pr)
                                     - OMB * (x + ls) * pr;
                        }
                    }
                }
            }
        }
    }
    __syncthreads();

    // ---------------- phase B: branch-free mask-FMA stream, batch-5 staging ----------
    const float4* x4p = (const float4*)logits + ((size_t)bs * NA + a0) * (NC / 4);
    float bgsum = 0.0f;
    #pragma unroll
    for (int g = 0; g < 5; g++) {
        float4 xs[5];
        float  ms[5];
        #pragma unroll
        for (int j = 0; j < 5; j++) {
            int i = t + (g * 5 + j) * 256;
            ms[j] = smask[i / 20];     // LDS, const-divisor magic mul
            xs[j] = x4p[i];
        }
        #pragma unroll
        for (int j = 0; j < 5; j++) {
            float xv[4] = {xs[j].x, xs[j].y, xs[j].z, xs[j].w};
            float tsum = 0.0f;
            #pragma unroll
            for (int jj = 0; jj < 4; jj++) {
                float x = xv[jj];
                float e = __expf(-x);
                float s = 1.0f + e;
                float pr = __builtin_amdgcn_rcpf(s);
                float ls = __logf(s);
                tsum += (x + ls) * pr;
            }
            bgsum = fmaf(ms[j], tsum, bgsum);
        }
    }
    float clssum = corrsum + OMB * bgsum;

    // wave shfl-reduce then cross-wave LDS then one atomic per block
    #pragma unroll
    for (int off = 32; off > 0; off >>= 1) {
        regsum += __shfl_xor(regsum, off);
        clssum += __shfl_xor(clssum, off);
        pcnt   += __shfl_xor(pcnt, off);
    }
    __shared__ float sf[4], sc[4];
    __shared__ int   si[4];
    int wave = t >> 6, lane = t & 63;
    if (lane == 0) { sf[wave] = regsum; sc[wave] = clssum; si[wave] = pcnt; }
    __syncthreads();
    if (t == 0) {
        atomicAdd(&acc[0], (double)(sf[0] + sf[1] + sf[2] + sf[3]));
        atomicAdd(&acc[1], (double)(sc[0] + sc[1] + sc[2] + sc[3]));
        atomicAdd(npos, si[0] + si[1] + si[2] + si[3]);
    }
}

// ---------------- kernel 3: ego focal loss + final combine ----------------
__global__ void k_final(const float* __restrict__ ego_preds, const int* __restrict__ ego_labels,
                        const double* __restrict__ acc, const int* __restrict__ npos,
                        float* __restrict__ out) {
    __shared__ float scol[NCE];
    __shared__ float sred[128];
    __shared__ int   sval[128];
    const float EPSF = 1e-7f;
    int t = threadIdx.x;
    if (t < NCE) {
        float c = 0.0f;
        for (int i = 0; i < NBS; i++) {
            int l = ego_labels[i];
            if (l > -1 && l == t) c = 1.0f;
        }
        scol[t] = c;
    }
    __syncthreads();

    float term = 0.0f;
    if (t < NBS * NCE) {
        int bs = t / NCE, e = t % NCE;
        int lbl = ego_labels[bs];
        if (lbl > -1) {
            float x = ego_preds[t];
            float ep = 1.0f / (1.0f + expf(-x));
            float oh = scol[e];
            float af = 0.25f * oh + 0.75f * (1.0f - oh);
            float ept = ep * oh + (1.0f - ep) * (1.0f - oh);
            float epc = fminf(fmaxf(ep, EPSF), 1.0f - EPSF);
            float bce = -(oh * logf(epc) + (1.0f - oh) * log1pf(-epc));
            float om = 1.0f - ept;
            term = bce * af * om * om;
        }
    }
    sred[t] = term;
    sval[t] = (t < NBS && ego_labels[t] > -1) ? 1 : 0;
    __syncthreads();
    for (int off = 64; off > 0; off >>= 1) {
        if (t < off) { sred[t] += sred[t + off]; sval[t] += sval[t + off]; }
        __syncthreads();
    }
    if (t == 0) {
        float esum = sred[0];
        int ne = sval[0];
        float ego = (ne > 0) ? esum / (float)(ne > 1 ? ne : 1) : 0.0f;
        double npd = (double)(*npos);
        if (npd < 1.0) npd = 1.0;
        out[0] = (float)(acc[0] / (npd * 4.0));
        out[1] = (float)(acc[1] / npd / 8.0 + (double)ego / 4.0);
    }
}

// ---------------- host launch ----------------
extern "C" void kernel_launch(void* const* d_in, const int* in_sizes, int n_in,
                              void* d_out, int out_size, void* d_ws, size_t ws_size,
                              hipStream_t stream) {
    const float* confidence = (const float*)d_in[0];
    const float* ploc       = (const float*)d_in[1];
    const float* gtb        = (const float*)d_in[2];
    const float* gtl        = (const float*)d_in[3];
    const int*   counts     = (const int*)d_in[4];
    const float* anchors    = (const float*)d_in[5];
    const float* ego_preds  = (const float*)d_in[6];
    const int*   ego_labels = (const int*)d_in[7];
    const int*   cls_num    = (const int*)d_in[8];
    float* out = (float*)d_out;

    // workspace layout (16B aligned chunks)
    char* ws = (char*)d_ws;
    double* acc  = (double*)ws;                               // [0]=reg_sum, [1]=cls_sum
    int* npos    = (int*)(ws + 16);
    unsigned long long* chunkbest = (unsigned long long*)(ws + 64);   // 1200*20 u64 = 192000 B
    float* bt_iou = (float*)(ws + 64 + 192000);               // 16*24000 f32
    int*   bt_idx = (int*)(ws + 64 + 192000 + 1536000);       // 16*24000 i32

    k_iou<<<NBS * CPB, 256, 0, stream>>>(gtb, counts, anchors, bt_iou, bt_idx,
                                         chunkbest, acc, npos);
    k_match<<<NBS * CPB, 256, 0, stream>>>(gtb, counts, anchors, ploc, gtl, confidence,
                                           cls_num, chunkbest, bt_iou, bt_idx, acc, npos);
    k_final<<<1, 128, 0, stream>>>(ego_preds, ego_labels, acc, npos, out);
}